// Round 5
// baseline (40.559 us; speedup 1.0000x reference)
//
#include <hip/hip_runtime.h>
#include <math.h>

// out[b,c,y,x] = (1/50)*albedo * sum_m relu(n.l_m)*env*sin(phi_i)
// Antipodal pairing (i,j)<->(16-i,(j+16)&31):
//   light = n.W + sum_{pairs} |n.l_p| * hs_p   (0.5/50 folded into table)
// Factorized dot: n.l(i,j) = sp_i*(nx*st_j - nz*ct_j) + ny*cp_i (trig constexpr).
// h-table in SGPRs via s_load_dwordx16/x8, double-buffered, prefetched one j
// ahead so the per-j lgkmcnt(0) has a full 140-cycle FMA block of cover.

constexpr int HW    = 512 * 512;
constexpr int BLOCK = 256;
constexpr int PPT   = 2;

// sin/cos((k+1)*pi/16) for i-slots, sin/cos(j*pi/16) for theta
__device__ constexpr float SP[8] = {
    0.195090322f, 0.382683432f, 0.555570233f, 0.707106781f,
    0.831469612f, 0.923879533f, 0.980785280f, 1.0f };
__device__ constexpr float CP[8] = {
    0.980785280f, 0.923879533f, 0.831469612f, 0.707106781f,
    0.555570233f, 0.382683432f, 0.195090322f, 0.0f };
__device__ constexpr float ST[32] = {
    0.0f,          0.195090322f,  0.382683432f,  0.555570233f,
    0.707106781f,  0.831469612f,  0.923879533f,  0.980785280f,
    1.0f,          0.980785280f,  0.923879533f,  0.831469612f,
    0.707106781f,  0.555570233f,  0.382683432f,  0.195090322f,
    0.0f,         -0.195090322f, -0.382683432f, -0.555570233f,
   -0.707106781f, -0.831469612f, -0.923879533f, -0.980785280f,
   -1.0f,         -0.980785280f, -0.923879533f, -0.831469612f,
   -0.707106781f, -0.555570233f, -0.382683432f, -0.195090322f };
__device__ constexpr float CT[32] = {
    1.0f,          0.980785280f,  0.923879533f,  0.831469612f,
    0.707106781f,  0.555570233f,  0.382683432f,  0.195090322f,
    0.0f,         -0.195090322f, -0.382683432f, -0.555570233f,
   -0.707106781f, -0.831469612f, -0.923879533f, -0.980785280f,
   -1.0f,         -0.980785280f, -0.923879533f, -0.831469612f,
   -0.707106781f, -0.555570233f, -0.382683432f, -0.195090322f,
    0.0f,          0.195090322f,  0.382683432f,  0.555570233f,
    0.707106781f,  0.831469612f,  0.923879533f,  0.980785280f };

typedef float f32x16 __attribute__((ext_vector_type(16)));
typedef float f32x8  __attribute__((ext_vector_type(8)));

__device__ __forceinline__ void sload24(const float* p, f32x16& a, f32x8& b) {
    asm volatile("s_load_dwordx16 %0, %2, 0x0\n\t"
                 "s_load_dwordx8 %1, %2, 0x40"
                 : "=&s"(a), "=&s"(b) : "s"(p));
}
__device__ __forceinline__ void swait(f32x16& a, f32x8& b) {
    // outputs tied so consumers can't be hoisted above the wait
    asm volatile("s_waitcnt lgkmcnt(0)" : "+s"(a), "+s"(b));
}

__global__ __launch_bounds__(256)
void build_tab_kernel(const float* __restrict__ env, float* __restrict__ ws, int B)
{
    const int b = blockIdx.x;
    const int t = threadIdx.x;              // 32 j x 8 i-slots
    const int iidx = t & 7, j = t >> 3;
    const int i = iidx + 1;
    float* tab  = ws;                       // [B][32][32] (24 used per j-row)
    float* Wout = ws + (size_t)B * 32 * 32; // [B][9]

    __shared__ float Wred[4][9];
    float W[9];
    #pragma unroll
    for (int q = 0; q < 9; ++q) W[q] = 0.0f;

    float hr = 0.f, hg = 0.f, hb = 0.f;
    if (!(i == 8 && j >= 16)) {                              // row-8 pairs only j<16
        const int i2 = 16 - i, j2 = (j + 16) & 31;
        const float phi   = (float)i * 0.19634954084936207f; // pi/16
        const float theta = (float)j * 0.19634954084936207f;
        const float sp = sinf(phi),   cp = cosf(phi);
        const float st = sinf(theta), ct = cosf(theta);
        const float dx = st * sp, dy = cp, dz = -ct * sp;    // |l| = 1
        const float scale = sp * 0.01f;                      // sin(phi)*0.5/50
        const float* ea = env + ((size_t)(b * 16 + i ) * 32 + j ) * 3;
        const float* eb = env + ((size_t)(b * 16 + i2) * 32 + j2) * 3;
        hr = (ea[0] + eb[0]) * scale;
        hg = (ea[1] + eb[1]) * scale;
        hb = (ea[2] + eb[2]) * scale;
        const float hd0 = (ea[0] - eb[0]) * scale;
        const float hd1 = (ea[1] - eb[1]) * scale;
        const float hd2 = (ea[2] - eb[2]) * scale;
        W[0] = dx * hd0; W[1] = dx * hd1; W[2] = dx * hd2;
        W[3] = dy * hd0; W[4] = dy * hd1; W[5] = dy * hd2;
        W[6] = dz * hd0; W[7] = dz * hd1; W[8] = dz * hd2;
    }
    const size_t o = (size_t)b * 1024 + j * 32 + iidx * 3;
    tab[o] = hr; tab[o + 1] = hg; tab[o + 2] = hb;

    #pragma unroll
    for (int q = 0; q < 9; ++q) {
        float v = W[q];
        #pragma unroll
        for (int off = 32; off > 0; off >>= 1) v += __shfl_down(v, off);
        if ((t & 63) == 0) Wred[t >> 6][q] = v;
    }
    __syncthreads();
    if (t < 9) Wout[b * 9 + t] = Wred[0][t] + Wred[1][t] + Wred[2][t] + Wred[3][t];
}

__device__ __forceinline__ void accum8(const f32x16& h0, const f32x8& h1,
                                       float u, const float* nyc,
                                       float& s0, float& s1, float& s2)
{
    #pragma unroll
    for (int i = 0; i < 8; ++i) {
        const float d = fmaf(SP[i], u, nyc[i]);
        const float a = fabsf(d);                            // operand modifier
        const float hr = (3 * i     < 16) ? h0[3 * i]     : h1[3 * i - 16];
        const float hg = (3 * i + 1 < 16) ? h0[3 * i + 1] : h1[3 * i + 1 - 16];
        const float hb = (3 * i + 2 < 16) ? h0[3 * i + 2] : h1[3 * i + 2 - 16];
        s0 = fmaf(a, hr, s0);
        s1 = fmaf(a, hg, s1);
        s2 = fmaf(a, hb, s2);
    }
}

__global__ __launch_bounds__(BLOCK)
void env_render_kernel(const float* __restrict__ normal,
                       const float* __restrict__ albedo,
                       const float* __restrict__ tab,    // [B][32][32]
                       const float* __restrict__ Wmat,   // [B][9]
                       float* __restrict__ out)
{
    const int b    = blockIdx.y;
    const int pix0 = blockIdx.x * (BLOCK * PPT) + threadIdx.x;

    float nx[PPT], ny[PPT], nz[PPT];
    float al[PPT][3];
    #pragma unroll
    for (int k = 0; k < PPT; ++k) {
        const int pix = pix0 + k * BLOCK;
        const float* p = normal + ((size_t)b * HW + pix) * 3;
        nx[k] = fmaf(p[2], 2.0f, -1.0f);                     // channel flip + decode
        ny[k] = fmaf(p[1], 2.0f, -1.0f);
        nz[k] = fmaf(p[0], 2.0f, -1.0f);
        const size_t base = (size_t)b * 3 * HW + pix;
        al[k][0] = albedo[base];
        al[k][1] = albedo[base + HW];
        al[k][2] = albedo[base + 2 * HW];
    }

    float Wl[9];
    #pragma unroll
    for (int q = 0; q < 9; ++q) Wl[q] = Wmat[b * 9 + q];

    float nyc[PPT][8];
    #pragma unroll
    for (int k = 0; k < PPT; ++k)
        #pragma unroll
        for (int i = 0; i < 8; ++i) nyc[k][i] = ny[k] * CP[i];

    float s[PPT][3];
    #pragma unroll
    for (int k = 0; k < PPT; ++k) s[k][0] = s[k][1] = s[k][2] = 0.f;

    const float* tb = tab + (size_t)b * 1024;

    f32x16 A0, B0; f32x8 A1, B1;
    sload24(tb, A0, A1);                                     // prefetch j=0

    #pragma unroll
    for (int jj = 0; jj < 32; jj += 2) {
        // ---- even j: buffer A ----
        swait(A0, A1);
        sload24(tb + (jj + 1) * 32, B0, B1);                 // prefetch j+1
        {
            #pragma unroll
            for (int k = 0; k < PPT; ++k) {
                const float u = fmaf(nx[k], ST[jj], -nz[k] * CT[jj]);
                accum8(A0, A1, u, nyc[k], s[k][0], s[k][1], s[k][2]);
            }
        }
        __builtin_amdgcn_sched_barrier(0);
        // ---- odd j: buffer B ----
        swait(B0, B1);
        if (jj + 2 < 32) sload24(tb + (jj + 2) * 32, A0, A1); // prefetch j+2
        {
            #pragma unroll
            for (int k = 0; k < PPT; ++k) {
                const float u = fmaf(nx[k], ST[jj + 1], -nz[k] * CT[jj + 1]);
                accum8(B0, B1, u, nyc[k], s[k][0], s[k][1], s[k][2]);
            }
        }
        __builtin_amdgcn_sched_barrier(0);
    }

    #pragma unroll
    for (int k = 0; k < PPT; ++k) {
        const int pix = pix0 + k * BLOCK;
        const size_t base = (size_t)b * 3 * HW + pix;
        const float l0 = s[k][0] + fmaf(nx[k], Wl[0], fmaf(ny[k], Wl[3], nz[k] * Wl[6]));
        const float l1 = s[k][1] + fmaf(nx[k], Wl[1], fmaf(ny[k], Wl[4], nz[k] * Wl[7]));
        const float l2 = s[k][2] + fmaf(nx[k], Wl[2], fmaf(ny[k], Wl[5], nz[k] * Wl[8]));
        out[base]          = l0 * al[k][0];
        out[base + HW]     = l1 * al[k][1];
        out[base + 2 * HW] = l2 * al[k][2];
    }
}

extern "C" void kernel_launch(void* const* d_in, const int* in_sizes, int n_in,
                              void* d_out, int out_size, void* d_ws, size_t ws_size,
                              hipStream_t stream)
{
    const float* env    = (const float*)d_in[0];
    const float* normal = (const float*)d_in[1];
    const float* albedo = (const float*)d_in[2];
    float* out          = (float*)d_out;
    float* ws           = (float*)d_ws;

    const int B = in_sizes[0] / (16 * 32 * 3);               // = 2

    build_tab_kernel<<<dim3(B), 256, 0, stream>>>(env, ws, B);

    const float* tab  = ws;
    const float* Wmat = ws + (size_t)B * 1024;

    dim3 grid(HW / (BLOCK * PPT), B);                        // (512, 2)
    env_render_kernel<<<grid, BLOCK, 0, stream>>>(normal, albedo, tab, Wmat, out);
}

// Round 6
// 25.178 us; speedup vs baseline: 1.6109x; 1.6109x over previous
//
#include <hip/hip_runtime.h>
#include <math.h>

// out[b,c,y,x] = (1/50)*albedo * sum_m relu(n.l_m)*env*sin(phi_i)
// Antipodal pairing (i,j)<->(16-i,(j+16)&31), same sin(phi):
//   light = n.W + sum_{240 pairs} |n.l_p| * hs_p    (0.5/50 folded into table)
// Factorized dot: n.l(i,j) = sp_i*(nx*st_j - nz*ct_j) + ny*cp_i, trig constexpr.
// h-table read through a uniform-indexed const __restrict__ pointer -> compiler
// emits s_load (SGPR operand feeds the FMA directly, no per-lane replication)
// and schedules/hoists the loads itself. NO inline asm (R5 lesson).

constexpr int HW    = 512 * 512;
constexpr int BLOCK = 256;
constexpr int PPT   = 2;

// sin/cos((k+1)*pi/16) for i-slots 0..7 (i = slot+1)
__device__ constexpr float SP[8] = {
    0.195090322f, 0.382683432f, 0.555570233f, 0.707106781f,
    0.831469612f, 0.923879533f, 0.980785280f, 1.0f };
__device__ constexpr float CP[8] = {
    0.980785280f, 0.923879533f, 0.831469612f, 0.707106781f,
    0.555570233f, 0.382683432f, 0.195090322f, 0.0f };
__device__ constexpr float ST[32] = {
    0.0f,          0.195090322f,  0.382683432f,  0.555570233f,
    0.707106781f,  0.831469612f,  0.923879533f,  0.980785280f,
    1.0f,          0.980785280f,  0.923879533f,  0.831469612f,
    0.707106781f,  0.555570233f,  0.382683432f,  0.195090322f,
    0.0f,         -0.195090322f, -0.382683432f, -0.555570233f,
   -0.707106781f, -0.831469612f, -0.923879533f, -0.980785280f,
   -1.0f,         -0.980785280f, -0.923879533f, -0.831469612f,
   -0.707106781f, -0.555570233f, -0.382683432f, -0.195090322f };
__device__ constexpr float CT[32] = {
    1.0f,          0.980785280f,  0.923879533f,  0.831469612f,
    0.707106781f,  0.555570233f,  0.382683432f,  0.195090322f,
    0.0f,         -0.195090322f, -0.382683432f, -0.555570233f,
   -0.707106781f, -0.831469612f, -0.923879533f, -0.980785280f,
   -1.0f,         -0.980785280f, -0.923879533f, -0.831469612f,
   -0.707106781f, -0.555570233f, -0.382683432f, -0.195090322f,
    0.0f,          0.195090322f,  0.382683432f,  0.555570233f,
    0.707106781f,  0.831469612f,  0.923879533f,  0.980785280f };

__global__ __launch_bounds__(256)
void build_tab_kernel(const float* __restrict__ env, float* __restrict__ ws, int B)
{
    const int b = blockIdx.x;
    const int t = threadIdx.x;              // 32 j x 8 i-slots
    const int iidx = t & 7, j = t >> 3;
    const int i = iidx + 1;
    float* tab  = ws;                       // [B][32][24]
    float* Wout = ws + (size_t)B * 32 * 24; // [B][9]

    __shared__ float Wred[4][9];
    float W[9];
    #pragma unroll
    for (int q = 0; q < 9; ++q) W[q] = 0.0f;

    float hr = 0.f, hg = 0.f, hb = 0.f;
    if (!(i == 8 && j >= 16)) {                              // row-8 pairs only j<16
        const int i2 = 16 - i, j2 = (j + 16) & 31;
        const float phi   = (float)i * 0.19634954084936207f; // pi/16
        const float theta = (float)j * 0.19634954084936207f;
        const float sp = sinf(phi),   cp = cosf(phi);
        const float st = sinf(theta), ct = cosf(theta);
        const float dx = st * sp, dy = cp, dz = -ct * sp;    // |l| = 1
        const float scale = sp * 0.01f;                      // sin(phi)*0.5/50
        const float* ea = env + ((size_t)(b * 16 + i ) * 32 + j ) * 3;
        const float* eb = env + ((size_t)(b * 16 + i2) * 32 + j2) * 3;
        hr = (ea[0] + eb[0]) * scale;
        hg = (ea[1] + eb[1]) * scale;
        hb = (ea[2] + eb[2]) * scale;
        const float hd0 = (ea[0] - eb[0]) * scale;
        const float hd1 = (ea[1] - eb[1]) * scale;
        const float hd2 = (ea[2] - eb[2]) * scale;
        W[0] = dx * hd0; W[1] = dx * hd1; W[2] = dx * hd2;
        W[3] = dy * hd0; W[4] = dy * hd1; W[5] = dy * hd2;
        W[6] = dz * hd0; W[7] = dz * hd1; W[8] = dz * hd2;
    }
    const size_t o = (size_t)b * 768 + j * 24 + iidx * 3;
    tab[o] = hr; tab[o + 1] = hg; tab[o + 2] = hb;

    #pragma unroll
    for (int q = 0; q < 9; ++q) {
        float v = W[q];
        #pragma unroll
        for (int off = 32; off > 0; off >>= 1) v += __shfl_down(v, off);
        if ((t & 63) == 0) Wred[t >> 6][q] = v;
    }
    __syncthreads();
    if (t < 9) Wout[b * 9 + t] = Wred[0][t] + Wred[1][t] + Wred[2][t] + Wred[3][t];
}

__global__ __launch_bounds__(BLOCK)
void env_render_kernel(const float* __restrict__ normal,
                       const float* __restrict__ albedo,
                       const float* __restrict__ tab,    // [B][32][24]
                       const float* __restrict__ Wmat,   // [B][9]
                       float* __restrict__ out)
{
    const int b    = blockIdx.y;
    const int pix0 = blockIdx.x * (BLOCK * PPT) + threadIdx.x;

    float nx[PPT], ny[PPT], nz[PPT];
    float al[PPT][3];
    #pragma unroll
    for (int k = 0; k < PPT; ++k) {
        const int pix = pix0 + k * BLOCK;
        const float* p = normal + ((size_t)b * HW + pix) * 3;
        nx[k] = fmaf(p[2], 2.0f, -1.0f);                     // channel flip + decode
        ny[k] = fmaf(p[1], 2.0f, -1.0f);
        nz[k] = fmaf(p[0], 2.0f, -1.0f);
        const size_t base = (size_t)b * 3 * HW + pix;
        al[k][0] = albedo[base];
        al[k][1] = albedo[base + HW];
        al[k][2] = albedo[base + 2 * HW];
    }

    float Wl[9];
    #pragma unroll
    for (int q = 0; q < 9; ++q) Wl[q] = Wmat[b * 9 + q];     // uniform -> s_load

    float nyc[PPT][8];
    #pragma unroll
    for (int k = 0; k < PPT; ++k)
        #pragma unroll
        for (int i = 0; i < 8; ++i) nyc[k][i] = ny[k] * CP[i];

    float s0[PPT], s1[PPT], s2[PPT];
    #pragma unroll
    for (int k = 0; k < PPT; ++k) s0[k] = s1[k] = s2[k] = 0.f;

    const float* __restrict__ tb = tab + (size_t)b * 768;    // uniform base

    #pragma unroll
    for (int j = 0; j < 32; ++j) {
        // 24 uniform loads; all indices compile-time -> registers (SGPRs),
        // compiler clusters them into s_load_dwordx* and places lgkmcnt.
        float hh[24];
        #pragma unroll
        for (int q = 0; q < 24; ++q) hh[q] = tb[j * 24 + q];

        #pragma unroll
        for (int k = 0; k < PPT; ++k) {
            const float u = fmaf(nx[k], ST[j], -nz[k] * CT[j]);
            #pragma unroll
            for (int i = 0; i < 8; ++i) {
                const float d = fmaf(SP[i], u, nyc[k][i]);   // i=7: folds to u
                const float a = fabsf(d);                    // operand modifier
                s0[k] = fmaf(a, hh[3 * i],     s0[k]);
                s1[k] = fmaf(a, hh[3 * i + 1], s1[k]);
                s2[k] = fmaf(a, hh[3 * i + 2], s2[k]);
            }
        }
    }

    #pragma unroll
    for (int k = 0; k < PPT; ++k) {
        const int pix = pix0 + k * BLOCK;
        const size_t base = (size_t)b * 3 * HW + pix;
        const float l0 = s0[k] + fmaf(nx[k], Wl[0], fmaf(ny[k], Wl[3], nz[k] * Wl[6]));
        const float l1 = s1[k] + fmaf(nx[k], Wl[1], fmaf(ny[k], Wl[4], nz[k] * Wl[7]));
        const float l2 = s2[k] + fmaf(nx[k], Wl[2], fmaf(ny[k], Wl[5], nz[k] * Wl[8]));
        out[base]          = l0 * al[k][0];
        out[base + HW]     = l1 * al[k][1];
        out[base + 2 * HW] = l2 * al[k][2];
    }
}

extern "C" void kernel_launch(void* const* d_in, const int* in_sizes, int n_in,
                              void* d_out, int out_size, void* d_ws, size_t ws_size,
                              hipStream_t stream)
{
    const float* env    = (const float*)d_in[0];
    const float* normal = (const float*)d_in[1];
    const float* albedo = (const float*)d_in[2];
    float* out          = (float*)d_out;
    float* ws           = (float*)d_ws;

    const int B = in_sizes[0] / (16 * 32 * 3);               // = 2

    build_tab_kernel<<<dim3(B), 256, 0, stream>>>(env, ws, B);

    const float* tab  = ws;
    const float* Wmat = ws + (size_t)B * 768;

    dim3 grid(HW / (BLOCK * PPT), B);                        // (512, 2)
    env_render_kernel<<<grid, BLOCK, 0, stream>>>(normal, albedo, tab, Wmat, out);
}